// Round 12
// baseline (2474.917 us; speedup 1.0000x reference)
//
#include <hip/hip_runtime.h>
#include <hip/hip_bf16.h>

// ---------- common ----------
typedef short bf16x8 __attribute__((ext_vector_type(8)));
typedef float f32x4 __attribute__((ext_vector_type(4)));

__device__ __forceinline__ unsigned short f2bf(float f) {
  union { float f; unsigned u; } un; un.f = f;
  unsigned r = un.u + 0x7fffu + ((un.u >> 16) & 1u);
  return (unsigned short)(r >> 16);
}

__device__ __forceinline__ void gl_lds16(const void* g, void* l) {
  __builtin_amdgcn_global_load_lds(
      (const __attribute__((address_space(1))) void*)g,
      (__attribute__((address_space(3))) void*)l, 16, 0, 0);
}

// ---------- embedding ----------
__global__ __launch_bounds__(256) void embed_k(const int* __restrict__ idx,
                                               const float* __restrict__ tok,
                                               const float* __restrict__ pos,
                                               float* __restrict__ x) {
  int m = blockIdx.x, t = threadIdx.x;
  int tk = idx[m];
  int tp = m & 1023;
  f32x4 a = __builtin_nontemporal_load((const f32x4*)(tok + (long)tk * 1024) + t);
  f32x4 p = ((const f32x4*)(pos + (long)tp * 1024))[t];
  a += p;
  ((f32x4*)(x + (long)m * 1024))[t] = a;
}

// ---------- layernorm: fp32 x -> bf16 out ----------
__global__ __launch_bounds__(256) void ln_k(const float* __restrict__ x,
                                            const float* __restrict__ g,
                                            const float* __restrict__ b,
                                            unsigned short* __restrict__ out) {
  int row = blockIdx.x, t = threadIdx.x;
  float4 v = ((const float4*)(x + (long)row * 1024))[t];
  float s = v.x + v.y + v.z + v.w;
  float ss = v.x * v.x + v.y * v.y + v.z * v.z + v.w * v.w;
#pragma unroll
  for (int d = 32; d; d >>= 1) { s += __shfl_xor(s, d, 64); ss += __shfl_xor(ss, d, 64); }
  __shared__ float red[8];
  int wave = t >> 6, lane = t & 63;
  if (lane == 0) { red[wave] = s; red[wave + 4] = ss; }
  __syncthreads();
  s = red[0] + red[1] + red[2] + red[3];
  ss = red[4] + red[5] + red[6] + red[7];
  float mu = s * (1.f / 1024.f);
  float var = ss * (1.f / 1024.f) - mu * mu;
  float rstd = rsqrtf(var + 1e-5f);
  float4 gv = ((const float4*)g)[t];
  float4 bv = ((const float4*)b)[t];
  ushort4 o;
  o.x = f2bf((v.x - mu) * rstd * gv.x + bv.x);
  o.y = f2bf((v.y - mu) * rstd * gv.y + bv.y);
  o.z = f2bf((v.z - mu) * rstd * gv.z + bv.z);
  o.w = f2bf((v.w - mu) * rstd * gv.w + bv.w);
  ((ushort4*)(out + (long)row * 1024))[t] = o;
}

// ---------- generic batched transpose fp32[R,C] -> bf16[C,R] (NT reads) ----------
__global__ __launch_bounds__(256) void tr_k(const float* __restrict__ in,
                                            unsigned short* __restrict__ out,
                                            int R, int C, long inStride, long outStride) {
  __shared__ float tile[32][33];
  int batch = blockIdx.z;
  int c0 = blockIdx.x * 32, r0 = blockIdx.y * 32;
  const float* ip = in + (long)batch * inStride;
  unsigned short* op = out + (long)batch * outStride;
  int tx = threadIdx.x, ty = threadIdx.y; // (32,8)
#pragma unroll
  for (int i = 0; i < 4; ++i)
    tile[ty + i * 8][tx] = __builtin_nontemporal_load(ip + (long)(r0 + ty + i * 8) * C + c0 + tx);
  __syncthreads();
#pragma unroll
  for (int i = 0; i < 4; ++i)
    op[(long)(c0 + ty + i * 8) * R + r0 + tx] = f2bf(tile[tx][ty + i * 8]);
}

// ---------- all-layer QKV weight transpose (NT reads) ----------
__global__ __launch_bounds__(256) void tr_qkv_k(const float* __restrict__ wq,
                                                const float* __restrict__ wk,
                                                const float* __restrict__ wv,
                                                unsigned short* __restrict__ out) {
  __shared__ float tile[32][33];
  int z = blockIdx.z;                 // 0..383
  int tsel = z >> 7, rem = z & 127;
  int l = rem >> 4, h = rem & 15;
  const float* ip = (tsel == 0 ? wq : tsel == 1 ? wk : wv) + (long)rem * 65536;
  unsigned short* op = out + (long)l * (3072 * 1024) + (long)tsel * (1024 * 1024) +
                       (long)h * 65536;
  int c0 = blockIdx.x * 32, r0 = blockIdx.y * 32;
  int tx = threadIdx.x, ty = threadIdx.y;
#pragma unroll
  for (int i = 0; i < 4; ++i)
    tile[ty + i * 8][tx] = __builtin_nontemporal_load(ip + (long)(r0 + ty + i * 8) * 64 + c0 + tx);
  __syncthreads();
#pragma unroll
  for (int i = 0; i < 4; ++i)
    op[(long)(c0 + ty + i * 8) * 1024 + r0 + tx] = f2bf(tile[tx][ty + i * 8]);
}

// ---------- 128^2 GEMM (high-occupancy workhorse: 4-5 blocks/CU) ----------
// EPI 0: bf16 out. EPI 1: f32 out = acc+bias+res. EPI 2: bf16 out = gelu(acc+bias).
template <int EPI>
__global__ __launch_bounds__(256) void gemm_bt(const unsigned short* __restrict__ A,
                                               const unsigned short* __restrict__ Bt,
                                               float* __restrict__ outf,
                                               unsigned short* __restrict__ outb,
                                               const float* __restrict__ bias,
                                               const float* __restrict__ res,
                                               int M, int N, int K) {
  __shared__ __align__(16) unsigned short sA[128 * 64];
  __shared__ __align__(16) unsigned short sB[128 * 64];
  const int t = threadIdx.x;
  const int wave = t >> 6, lane = t & 63;

  const int gx = gridDim.x, gy = gridDim.y;
  const int nwg = gx * gy;
  const int bid = blockIdx.y * gx + blockIdx.x;
  const int qd = nwg >> 3, rd = nwg & 7;
  const int xcd = bid & 7, off = bid >> 3;
  const int swz = (xcd < rd ? xcd * (qd + 1) : rd * (qd + 1) + (xcd - rd) * qd) + off;
  const int m0 = (swz % gy) << 7, n0 = (swz / gy) << 7;

  const int wm = (wave >> 1) * 64, wn = (wave & 1) * 64;
  const f32x4 z4 = {0.f, 0.f, 0.f, 0.f};
  f32x4 acc[4][4];
#pragma unroll
  for (int i = 0; i < 4; ++i)
#pragma unroll
    for (int j = 0; j < 4; ++j) acc[i][j] = z4;

  const int srow = t >> 3;
  const int scb = (((t & 7) ^ ((t >> 3) & 7)) << 4);
  const char* Ab = (const char*)A;
  const char* Bb = (const char*)Bt;
  char* sAb = (char*)sA;
  char* sBb = (char*)sB;
  const long ldb2 = (long)K * 2;
  const int pc0 = (((lane >> 4) ^ (lane & 7)) << 4);

  for (int k0 = 0; k0 < K; k0 += 64) {
    __syncthreads();
#pragma unroll
    for (int i = 0; i < 4; ++i) {
      int row = i * 32 + srow;
      gl_lds16(Ab + (long)(m0 + row) * ldb2 + (long)k0 * 2 + scb,
               sAb + i * 4096 + wave * 1024);
      gl_lds16(Bb + (long)(n0 + row) * ldb2 + (long)k0 * 2 + scb,
               sBb + i * 4096 + wave * 1024);
    }
    __syncthreads();
#pragma unroll
    for (int kk = 0; kk < 2; ++kk) {
      const int kb = pc0 ^ (kk << 6);
      bf16x8 af[4], bfr[4];
#pragma unroll
      for (int f = 0; f < 4; ++f) {
        int ra = wm + f * 16 + (lane & 15);
        af[f] = *(const bf16x8*)(sAb + ra * 128 + kb);
        int rb = wn + f * 16 + (lane & 15);
        bfr[f] = *(const bf16x8*)(sBb + rb * 128 + kb);
      }
#pragma unroll
      for (int fm = 0; fm < 4; ++fm)
#pragma unroll
        for (int fn = 0; fn < 4; ++fn)
          acc[fm][fn] = __builtin_amdgcn_mfma_f32_16x16x32_bf16(af[fm], bfr[fn], acc[fm][fn], 0, 0, 0);
    }
  }
  const int rl = (lane >> 4) << 2;
  const int cl = lane & 15;
#pragma unroll
  for (int fm = 0; fm < 4; ++fm) {
#pragma unroll
    for (int fn = 0; fn < 4; ++fn) {
#pragma unroll
      for (int r = 0; r < 4; ++r) {
        int m = m0 + wm + fm * 16 + rl + r;
        int n = n0 + wn + fn * 16 + cl;
        float v = acc[fm][fn][r];
        if (EPI == 1 || EPI == 2) v += bias[n];
        if (EPI == 1) v += res[(long)m * N + n];
        if (EPI == 2) v = 0.5f * v * (1.f + erff(v * 0.70710678118f));
        if (EPI == 1) outf[(long)m * N + n] = v;
        else outb[(long)m * N + n] = f2bf(v);
      }
    }
  }
}

// ---------- 256^2 8-phase GEMM (BK=64, 2 dbuf, counted vmcnt) — head only ----------
// EPI 3: f32 out = acc+bias.
template <int EPI>
__global__ __launch_bounds__(512, 1) void gemm256(const unsigned short* __restrict__ A,
                                                  const unsigned short* __restrict__ Bt,
                                                  float* __restrict__ outf,
                                                  unsigned short* __restrict__ outb,
                                                  const float* __restrict__ bias,
                                                  int M, int N, int K) {
  __shared__ __align__(16) char smem[131072];  // 2 bufs x (A 32K + B 32K)
  const int t = threadIdx.x;
  const int wave = t >> 6, lane = t & 63;

  const int gx = gridDim.x, gy = gridDim.y;
  const int nwg = gx * gy;
  const int bid = blockIdx.y * gx + blockIdx.x;
  const int qd = nwg >> 3, rd = nwg & 7;
  const int xcd = bid & 7, off = bid >> 3;
  const int swz = (xcd < rd ? xcd * (qd + 1) : rd * (qd + 1) + (xcd - rd) * qd) + off;
  const int m0 = (swz % gy) << 8, n0 = (swz / gy) << 8;

  const int wm = (wave >> 2) << 7;  // 0 / 128
  const int wn = (wave & 3) << 6;   // 0,64,128,192
  const int KT2 = K >> 7;           // iterations; 2 K-tiles (BK=64) each

  const f32x4 z4 = {0.f, 0.f, 0.f, 0.f};
  f32x4 acc[8][4];
#pragma unroll
  for (int i = 0; i < 8; ++i)
#pragma unroll
    for (int j = 0; j < 4; ++j) acc[i][j] = z4;

  const int sck = (((t & 7) ^ ((t >> 3) & 7)) << 4);   // pre-swizzled src chunk bytes
  const long ldb = (long)K * 2;
  const char* Abase = (const char*)A + (long)(m0 + (t >> 3)) * ldb + sck;
  const char* Bbase = (const char*)Bt + (long)(n0 + (t >> 3)) * ldb + sck;

#define STG(base, tt, h, boff)                                              \
  { char* d = smem + (((tt) & 1) << 16) + (boff) + ((h) << 14) + wave * 1024; \
    const char* s = (base) + (long)((h) * 128) * ldb + ((long)(tt) << 7);     \
    gl_lds16(s, d); gl_lds16(s + (ldb << 6), d + 8192); }

  STG(Bbase, 0, 0, 32768); STG(Bbase, 0, 1, 32768);
  STG(Abase, 0, 0, 0);     STG(Abase, 0, 1, 0);
  STG(Bbase, 1, 0, 32768); STG(Bbase, 1, 1, 32768);
  STG(Abase, 1, 0, 0);
  asm volatile("s_waitcnt vmcnt(6)" ::: "memory");
  __builtin_amdgcn_sched_barrier(0);
  __builtin_amdgcn_s_barrier();

  const int la15 = lane & 15;
  const int pck0 = (((lane >> 4) ^ (la15 & 7)) << 4);  // phys chunk, kh=0
  const int pck1 = pck0 ^ 64;                          // kh=1

#define DS_A(q)                                                              \
  a00 = *(const bf16x8*)(bA + (wm + ((q) * 2) * 16 + la15) * 128 + pck0);    \
  a01 = *(const bf16x8*)(bA + (wm + ((q) * 2) * 16 + la15) * 128 + pck1);    \
  a10 = *(const bf16x8*)(bA + (wm + ((q) * 2 + 1) * 16 + la15) * 128 + pck0);\
  a11 = *(const bf16x8*)(bA + (wm + ((q) * 2 + 1) * 16 + la15) * 128 + pck1);

#define MFMA_Q(q)                                                                              \
  __builtin_amdgcn_s_setprio(1);                                                               \
  { _Pragma("unroll") for (int nf = 0; nf < 4; ++nf) {                                         \
      acc[(q)*2][nf]     = __builtin_amdgcn_mfma_f32_16x16x32_bf16(a00, bfr[nf][0], acc[(q)*2][nf], 0, 0, 0);     \
      acc[(q)*2][nf]     = __builtin_amdgcn_mfma_f32_16x16x32_bf16(a01, bfr[nf][1], acc[(q)*2][nf], 0, 0, 0);     \
      acc[(q)*2 + 1][nf] = __builtin_amdgcn_mfma_f32_16x16x32_bf16(a10, bfr[nf][0], acc[(q)*2 + 1][nf], 0, 0, 0); \
      acc[(q)*2 + 1][nf] = __builtin_amdgcn_mfma_f32_16x16x32_bf16(a11, bfr[nf][1], acc[(q)*2 + 1][nf], 0, 0, 0); \
  } }                                                                                          \
  __builtin_amdgcn_s_setprio(0);

#define BAR_LGKM()                                    \
  __builtin_amdgcn_s_barrier();                       \
  asm volatile("s_waitcnt lgkmcnt(0)" ::: "memory");  \
  __builtin_amdgcn_sched_barrier(0);

  for (int it = 0; it < KT2; ++it) {
    const bool more = (it + 1 < KT2);
#pragma unroll
    for (int g = 0; g < 2; ++g) {
      const int tt = 2 * it + g;
      const char* bA = smem + ((tt & 1) << 16);
      const char* bB = bA + 32768;
      bf16x8 bfr[4][2], a00, a01, a10, a11;

#pragma unroll
      for (int nf = 0; nf < 4; ++nf) {
        bfr[nf][0] = *(const bf16x8*)(bB + (wn + nf * 16 + la15) * 128 + pck0);
        bfr[nf][1] = *(const bf16x8*)(bB + (wn + nf * 16 + la15) * 128 + pck1);
      }
      DS_A(0);
      if (g == 0) { STG(Abase, tt + 1, 1, 0); }
      else if (more) { STG(Abase, tt + 1, 1, 0); }
      asm volatile("s_waitcnt lgkmcnt(8)" ::: "memory");
      BAR_LGKM();
      MFMA_Q(0);
      __builtin_amdgcn_s_barrier();

      DS_A(1);
      if (more) { STG(Bbase, tt + 2, 0, 32768); }
      BAR_LGKM();
      MFMA_Q(1);
      __builtin_amdgcn_s_barrier();

      DS_A(2);
      if (more) { STG(Bbase, tt + 2, 1, 32768); }
      BAR_LGKM();
      MFMA_Q(2);
      __builtin_amdgcn_s_barrier();

      DS_A(3);
      if (more) { STG(Abase, tt + 2, 0, 0); }
      BAR_LGKM();
      MFMA_Q(3);
      if (g == 0) {
        if (more) { asm volatile("s_waitcnt vmcnt(6)" ::: "memory"); }
        else      { asm volatile("s_waitcnt vmcnt(0)" ::: "memory"); }
        __builtin_amdgcn_sched_barrier(0);
      } else if (more) {
        asm volatile("s_waitcnt vmcnt(6)" ::: "memory");
        __builtin_amdgcn_sched_barrier(0);
      }
      __builtin_amdgcn_s_barrier();
    }
  }
#undef STG
#undef DS_A
#undef MFMA_Q
#undef BAR_LGKM

  const int rl = (lane >> 4) << 2;
#pragma unroll
  for (int fm = 0; fm < 8; ++fm) {
#pragma unroll
    for (int r = 0; r < 4; ++r) {
      int m = m0 + wm + fm * 16 + rl + r;
#pragma unroll
      for (int fn = 0; fn < 4; ++fn) {
        int n = n0 + wn + fn * 16 + la15;
        float v = acc[fm][fn][r];
        if (EPI == 3) v += bias[n];
        if (EPI == 3) outf[(long)m * N + n] = v;
        else outb[(long)m * N + n] = f2bf(v);
      }
    }
  }
}

// ---------- causal flash attention, paired q-tiles for uniform block cost ----------
__global__ __launch_bounds__(256) void attn_k(const unsigned short* __restrict__ qkv,
                                              unsigned short* __restrict__ o) {
  const int pi = blockIdx.x;          // 0..7
  const int pair = blockIdx.y;
  const int b = pair >> 4, h = pair & 15;
  const int t = threadIdx.x, wave = t >> 6, lane = t & 63;
  __shared__ __align__(16) unsigned short sQ[64 * 64];
  __shared__ __align__(16) unsigned short sK[2][64 * 64];
  __shared__ __align__(16) unsigned short sV[2][64 * 64];   // transposed [e][j]
  __shared__ __align__(16) unsigned short sP[4][16 * 64];

  const long baseq = (long)b * (1024 * 3072) + (long)h * 64;
  const unsigned short* qp = qkv + baseq;
  const unsigned short* kp = qkv + baseq + 1024;
  const unsigned short* vp = qkv + baseq + 2048;
  const long baseo = (long)b * (1024 * 1024) + (long)h * 64;

  const int row0 = t >> 3, c0 = t & 7;
  const int row1 = (t + 256) >> 3, c1 = t & 7;
  const int qoff0 = ((c0 ^ (row0 & 7)) << 3);
  const int qoff1 = ((c1 ^ (row1 & 7)) << 3);

  const int qrow = wave * 16 + (lane & 15);
  const int qswz0 = ((lane >> 4) << 4) ^ ((qrow & 7) << 4);
  const int prow = lane & 15;
  const f32x4 z4 = {0.f, 0.f, 0.f, 0.f};

  for (int half = 0; half < 2; ++half) {
    const int qt = half ? (15 - pi) : pi;
    __syncthreads();   // protect LDS reuse across halves

    gl_lds16(qp + (long)(qt * 64 + row0) * 3072 + qoff0, (char*)sQ + wave * 1024);
    gl_lds16(qp + (long)(qt * 64 + row1) * 3072 + qoff1, (char*)sQ + 4096 + wave * 1024);
    gl_lds16(kp + (long)(0 + row0) * 3072 + qoff0, (char*)sK[0] + wave * 1024);
    gl_lds16(kp + (long)(0 + row1) * 3072 + qoff1, (char*)sK[0] + 4096 + wave * 1024);
    bf16x8 vr0 = *(const bf16x8*)(vp + (long)row0 * 3072 + (c0 << 3));
    bf16x8 vr1 = *(const bf16x8*)(vp + (long)row1 * 3072 + (c1 << 3));
    {
      char* vb = (char*)sV[0];
#pragma unroll
      for (int j = 0; j < 8; ++j) {
        int e0 = (c0 << 3) + j, e1 = (c1 << 3) + j;
        *(unsigned short*)(vb + e0 * 128 + ((row0 * 2) ^ ((e0 & 7) << 4))) = (unsigned short)vr0[j];
        *(unsigned short*)(vb + e1 * 128 + ((row1 * 2) ^ ((e1 & 7) << 4))) = (unsigned short)vr1[j];
      }
    }
    __syncthreads();

    float lst[4] = {0.f, 0.f, 0.f, 0.f};
    f32x4 oacc[4];
#pragma unroll
    for (int eb = 0; eb < 4; ++eb) oacc[eb] = z4;

    for (int kt = 0; kt <= qt; ++kt) {
      const int cur = kt & 1;

      bf16x8 aq[2];
#pragma unroll
      for (int kk = 0; kk < 2; ++kk)
        aq[kk] = *(const bf16x8*)((char*)sQ + qrow * 128 + ((kk << 6) ^ qswz0));
      f32x4 sf[4];
#pragma unroll
      for (int cb = 0; cb < 4; ++cb) {
        f32x4 s = z4;
        int kr = cb * 16 + (lane & 15);
        int kswz = ((kr & 7) << 4);
#pragma unroll
        for (int kk = 0; kk < 2; ++kk) {
          int e0 = (kk * 32 + ((lane >> 4) << 3)) * 2;
          bf16x8 bk = *(const bf16x8*)((char*)sK[cur] + kr * 128 + (e0 ^ kswz));
          s = __builtin_amdgcn_mfma_f32_16x16x32_bf16(aq[kk], bk, s, 0, 0, 0);
        }
        sf[cb] = s;
      }

      if (kt < qt) {
        const int nxt = cur ^ 1;
        const long krb = (long)((kt + 1) * 64);
        gl_lds16(kp + (krb + row0) * 3072 + qoff0, (char*)sK[nxt] + wave * 1024);
        gl_lds16(kp + (krb + row1) * 3072 + qoff1, (char*)sK[nxt] + 4096 + wave * 1024);
        vr0 = *(const bf16x8*)(vp + (krb + row0) * 3072 + (c0 << 3));
        vr1 = *(const bf16x8*)(vp + (krb + row1) * 3072 + (c1 << 3));
      }

      const bool diag = (kt == qt);
      unsigned short* pb = sP[wave];
#pragma unroll
      for (int r = 0; r < 4; ++r) {
        int qg = wave * 16 + ((lane >> 4) << 2) + r;
        int lr = ((lane >> 4) << 2) + r;
        float rs = 0.f;
#pragma unroll
        for (int cb = 0; cb < 4; ++cb) {
          float p;
          if (diag) {
            int kg = cb * 16 + (lane & 15);
            p = (kg > qg) ? 0.f : __expf(sf[cb][r] * 0.125f);
          } else {
            p = __expf(sf[cb][r] * 0.125f);
          }
          rs += p;
          int col = cb * 16 + (lane & 15);
          *(unsigned short*)((char*)pb + lr * 128 + ((col * 2) ^ ((lr & 7) << 4))) = f2bf(p);
        }
        lst[r] += rs;
      }

      bf16x8 ap[2];
#pragma unroll
      for (int kk = 0; kk < 2; ++kk) {
        int j0 = (kk * 32 + ((lane >> 4) << 3)) * 2;
        ap[kk] = *(const bf16x8*)((char*)pb + prow * 128 + (j0 ^ ((prow & 7) << 4)));
      }
#pragma unroll
      for (int eb = 0; eb < 4; ++eb) {
        int er = eb * 16 + (lane & 15);
        int eswz = ((er & 7) << 4);
#pragma unroll
        for (int kk = 0; kk < 2; ++kk) {
          int j0 = (kk * 32 + ((lane >> 4) << 3)) * 2;
          bf16x8 bv = *(const bf16x8*)((char*)sV[cur] + er * 128 + (j0 ^ eswz));
          oacc[eb] = __builtin_amdgcn_mfma_f32_16x16x32_bf16(ap[kk], bv, oacc[eb], 0, 0, 0);
        }
      }

      if (kt < qt) {
        char* vb = (char*)sV[cur ^ 1];
#pragma unroll
        for (int j = 0; j < 8; ++j) {
          int e0 = (c0 << 3) + j, e1 = (c1 << 3) + j;
          *(unsigned short*)(vb + e0 * 128 + ((row0 * 2) ^ ((e0 & 7) << 4))) = (unsigned short)vr0[j];
          *(unsigned short*)(vb + e1 * 128 + ((row1 * 2) ^ ((e1 & 7) << 4))) = (unsigned short)vr1[j];
        }
        __syncthreads();
      }
    }

#pragma unroll
    for (int r = 0; r < 4; ++r) {
      float l = lst[r];
#pragma unroll
      for (int d = 1; d < 16; d <<= 1) l += __shfl_xor(l, d, 64);
      float inv = 1.f / l;
      int qg = qt * 64 + wave * 16 + ((lane >> 4) << 2) + r;
#pragma unroll
      for (int eb = 0; eb < 4; ++eb) {
        int e = eb * 16 + (lane & 15);
        o[baseo + (long)qg * 1024 + e] = f2bf(oacc[eb][r] * inv);
      }
    }
  }
}

// ---------- host launch ----------
extern "C" void kernel_launch(void* const* d_in, const int* in_sizes, int n_in,
                              void* d_out, int out_size, void* d_ws, size_t ws_size,
                              hipStream_t stream) {
  const int* idx = (const int*)d_in[0];
  const float* tok = (const float*)d_in[1];
  const float* pos = (const float*)d_in[2];
  const float* Wq = (const float*)d_in[3];
  const float* Wk = (const float*)d_in[4];
  const float* Wv = (const float*)d_in[5];
  const float* Wo = (const float*)d_in[6];
  const float* bo = (const float*)d_in[7];
  const float* ln1g = (const float*)d_in[8];
  const float* ln1b = (const float*)d_in[9];
  const float* ln2g = (const float*)d_in[10];
  const float* ln2b = (const float*)d_in[11];
  const float* W1 = (const float*)d_in[12];
  const float* b1 = (const float*)d_in[13];
  const float* W2 = (const float*)d_in[14];
  const float* b2 = (const float*)d_in[15];
  const float* lnfg = (const float*)d_in[16];
  const float* lnfb = (const float*)d_in[17];
  const float* Wh = (const float*)d_in[18];
  const float* bh = (const float*)d_in[19];

  char* ws = (char*)d_ws;
  const long Mi = 1024 * 1024;
  float* x = (float*)ws;
  unsigned short* xn = (unsigned short*)(ws + 16 * Mi);
  unsigned short* qkv = (unsigned short*)(ws + 24 * Mi);
  unsigned short* ob = (unsigned short*)(ws + 48 * Mi);
  unsigned short* hmid = (unsigned short*)(ws + 24 * Mi);
  unsigned short* wqkvT = (unsigned short*)(ws + 56 * Mi);
  unsigned short* whT = (unsigned short*)(ws + 56 * Mi);   // alias (post-loop)

  // big-ws path: all-layer transposed weights; small path: per-layer buffers
  const bool bigws = (ws_size >= (size_t)250 * 1024 * 1024);
  unsigned short* wotA = (unsigned short*)(ws + 104 * Mi);  // 8 x 2 MiB  = 16 MiB
  unsigned short* w1tA = (unsigned short*)(ws + 120 * Mi);  // 8 x 8 MiB  = 64 MiB
  unsigned short* w2tA = (unsigned short*)(ws + 184 * Mi);  // 8 x 8 MiB  = 64 MiB
  unsigned short* wot1 = (unsigned short*)(ws + 104 * Mi);  // small path (per-layer)
  unsigned short* w1t1 = (unsigned short*)(ws + 106 * Mi);
  unsigned short* w2t1 = (unsigned short*)(ws + 114 * Mi);

  dim3 blk256(256), blk512(512), blkT(32, 8);

  embed_k<<<4096, blk256, 0, stream>>>(idx, tok, pos, x);
  tr_qkv_k<<<dim3(2, 32, 384), blkT, 0, stream>>>(Wq, Wk, Wv, wqkvT);
  if (bigws) {
    tr_k<<<dim3(32, 32, 8), blkT, 0, stream>>>(Wo, wotA, 1024, 1024, 1048576, 1048576);
    tr_k<<<dim3(128, 32, 8), blkT, 0, stream>>>(W1, w1tA, 1024, 4096, 4194304, 4194304);
    tr_k<<<dim3(32, 128, 8), blkT, 0, stream>>>(W2, w2tA, 4096, 1024, 4194304, 4194304);
  }

  for (int l = 0; l < 8; ++l) {
    const float* bo_l = bo + (long)l * 1024;
    const float* b1_l = b1 + (long)l * 4096;
    const float* b2_l = b2 + (long)l * 1024;
    const unsigned short* wqkv_l = wqkvT + (long)l * (3072 * 1024);

    const unsigned short* wot_l;
    const unsigned short* w1t_l;
    const unsigned short* w2t_l;
    if (bigws) {
      wot_l = wotA + (long)l * 1048576;
      w1t_l = w1tA + (long)l * 4194304;
      w2t_l = w2tA + (long)l * 4194304;
    } else {
      tr_k<<<dim3(32, 32, 1), blkT, 0, stream>>>(Wo + (long)l * 1048576, wot1, 1024, 1024, 0, 0);
      tr_k<<<dim3(128, 32, 1), blkT, 0, stream>>>(W1 + (long)l * 4194304, w1t1, 1024, 4096, 0, 0);
      tr_k<<<dim3(32, 128, 1), blkT, 0, stream>>>(W2 + (long)l * 4194304, w2t1, 4096, 1024, 0, 0);
      wot_l = wot1; w1t_l = w1t1; w2t_l = w2t1;
    }

    ln_k<<<4096, blk256, 0, stream>>>(x, ln1g + l * 1024, ln1b + l * 1024, xn);

    // fused QKV projection on the 128^2 high-occupancy kernel
    gemm_bt<0><<<dim3(24, 32), blk256, 0, stream>>>(xn, wqkv_l, nullptr, qkv, nullptr, nullptr, 4096, 3072, 1024);

    attn_k<<<dim3(8, 64), blk256, 0, stream>>>(qkv, ob);

    gemm_bt<1><<<dim3(8, 32), blk256, 0, stream>>>(ob, wot_l, x, nullptr, bo_l, x, 4096, 1024, 1024);

    ln_k<<<4096, blk256, 0, stream>>>(x, ln2g + l * 1024, ln2b + l * 1024, xn);

    gemm_bt<2><<<dim3(32, 32), blk256, 0, stream>>>(xn, w1t_l, nullptr, hmid, b1_l, nullptr, 4096, 4096, 1024);
    gemm_bt<1><<<dim3(8, 32), blk256, 0, stream>>>(hmid, w2t_l, x, nullptr, b2_l, x, 4096, 1024, 4096);
  }

  ln_k<<<4096, blk256, 0, stream>>>(x, lnfg, lnfb, xn);
  tr_k<<<dim3(1000, 32, 1), blkT, 0, stream>>>(Wh, whT, 1024, 32000, 0, 0);
  gemm256<3><<<dim3(125, 16), blk512, 0, stream>>>(xn, whT, (float*)d_out, nullptr, bh, 4096, 32000, 1024);
}

// Round 13
// 2376.588 us; speedup vs baseline: 1.0414x; 1.0414x over previous
//
#include <hip/hip_runtime.h>
#include <hip/hip_bf16.h>

// ---------- common ----------
typedef short bf16x8 __attribute__((ext_vector_type(8)));
typedef float f32x4 __attribute__((ext_vector_type(4)));

__device__ __forceinline__ unsigned short f2bf(float f) {
  union { float f; unsigned u; } un; un.f = f;
  unsigned r = un.u + 0x7fffu + ((un.u >> 16) & 1u);
  return (unsigned short)(r >> 16);
}

__device__ __forceinline__ void gl_lds16(const void* g, void* l) {
  __builtin_amdgcn_global_load_lds(
      (const __attribute__((address_space(1))) void*)g,
      (__attribute__((address_space(3))) void*)l, 16, 0, 0);
}

// ---------- embedding ----------
__global__ __launch_bounds__(256) void embed_k(const int* __restrict__ idx,
                                               const float* __restrict__ tok,
                                               const float* __restrict__ pos,
                                               float* __restrict__ x) {
  int m = blockIdx.x, t = threadIdx.x;
  int tk = idx[m];
  int tp = m & 1023;
  f32x4 a = __builtin_nontemporal_load((const f32x4*)(tok + (long)tk * 1024) + t);
  f32x4 p = ((const f32x4*)(pos + (long)tp * 1024))[t];
  a += p;
  ((f32x4*)(x + (long)m * 1024))[t] = a;
}

// ---------- layernorm: fp32 x -> bf16 out ----------
__global__ __launch_bounds__(256) void ln_k(const float* __restrict__ x,
                                            const float* __restrict__ g,
                                            const float* __restrict__ b,
                                            unsigned short* __restrict__ out) {
  int row = blockIdx.x, t = threadIdx.x;
  float4 v = ((const float4*)(x + (long)row * 1024))[t];
  float s = v.x + v.y + v.z + v.w;
  float ss = v.x * v.x + v.y * v.y + v.z * v.z + v.w * v.w;
#pragma unroll
  for (int d = 32; d; d >>= 1) { s += __shfl_xor(s, d, 64); ss += __shfl_xor(ss, d, 64); }
  __shared__ float red[8];
  int wave = t >> 6, lane = t & 63;
  if (lane == 0) { red[wave] = s; red[wave + 4] = ss; }
  __syncthreads();
  s = red[0] + red[1] + red[2] + red[3];
  ss = red[4] + red[5] + red[6] + red[7];
  float mu = s * (1.f / 1024.f);
  float var = ss * (1.f / 1024.f) - mu * mu;
  float rstd = rsqrtf(var + 1e-5f);
  float4 gv = ((const float4*)g)[t];
  float4 bv = ((const float4*)b)[t];
  ushort4 o;
  o.x = f2bf((v.x - mu) * rstd * gv.x + bv.x);
  o.y = f2bf((v.y - mu) * rstd * gv.y + bv.y);
  o.z = f2bf((v.z - mu) * rstd * gv.z + bv.z);
  o.w = f2bf((v.w - mu) * rstd * gv.w + bv.w);
  ((ushort4*)(out + (long)row * 1024))[t] = o;
}

// ---------- generic batched transpose fp32[R,C] -> bf16[C,R] (NT reads) ----------
__global__ __launch_bounds__(256) void tr_k(const float* __restrict__ in,
                                            unsigned short* __restrict__ out,
                                            int R, int C, long inStride, long outStride) {
  __shared__ float tile[32][33];
  int batch = blockIdx.z;
  int c0 = blockIdx.x * 32, r0 = blockIdx.y * 32;
  const float* ip = in + (long)batch * inStride;
  unsigned short* op = out + (long)batch * outStride;
  int tx = threadIdx.x, ty = threadIdx.y; // (32,8)
#pragma unroll
  for (int i = 0; i < 4; ++i)
    tile[ty + i * 8][tx] = __builtin_nontemporal_load(ip + (long)(r0 + ty + i * 8) * C + c0 + tx);
  __syncthreads();
#pragma unroll
  for (int i = 0; i < 4; ++i)
    op[(long)(c0 + ty + i * 8) * R + r0 + tx] = f2bf(tile[tx][ty + i * 8]);
}

// ---------- all-layer QKV weight transpose (NT reads) ----------
__global__ __launch_bounds__(256) void tr_qkv_k(const float* __restrict__ wq,
                                                const float* __restrict__ wk,
                                                const float* __restrict__ wv,
                                                unsigned short* __restrict__ out) {
  __shared__ float tile[32][33];
  int z = blockIdx.z;                 // 0..383
  int tsel = z >> 7, rem = z & 127;
  int l = rem >> 4, h = rem & 15;
  const float* ip = (tsel == 0 ? wq : tsel == 1 ? wk : wv) + (long)rem * 65536;
  unsigned short* op = out + (long)l * (3072 * 1024) + (long)tsel * (1024 * 1024) +
                       (long)h * 65536;
  int c0 = blockIdx.x * 32, r0 = blockIdx.y * 32;
  int tx = threadIdx.x, ty = threadIdx.y;
#pragma unroll
  for (int i = 0; i < 4; ++i)
    tile[ty + i * 8][tx] = __builtin_nontemporal_load(ip + (long)(r0 + ty + i * 8) * 64 + c0 + tx);
  __syncthreads();
#pragma unroll
  for (int i = 0; i < 4; ++i)
    op[(long)(c0 + ty + i * 8) * 1024 + r0 + tx] = f2bf(tile[tx][ty + i * 8]);
}

// ---------- 128^2 GEMM (N=1024 shapes: 1024 blocks, high occupancy) ----------
// EPI 1: f32 out = acc+bias+res.
template <int EPI>
__global__ __launch_bounds__(256) void gemm_bt(const unsigned short* __restrict__ A,
                                               const unsigned short* __restrict__ Bt,
                                               float* __restrict__ outf,
                                               unsigned short* __restrict__ outb,
                                               const float* __restrict__ bias,
                                               const float* __restrict__ res,
                                               int M, int N, int K) {
  __shared__ __align__(16) unsigned short sA[128 * 64];
  __shared__ __align__(16) unsigned short sB[128 * 64];
  const int t = threadIdx.x;
  const int wave = t >> 6, lane = t & 63;

  const int gx = gridDim.x, gy = gridDim.y;
  const int nwg = gx * gy;
  const int bid = blockIdx.y * gx + blockIdx.x;
  const int qd = nwg >> 3, rd = nwg & 7;
  const int xcd = bid & 7, off = bid >> 3;
  const int swz = (xcd < rd ? xcd * (qd + 1) : rd * (qd + 1) + (xcd - rd) * qd) + off;
  const int m0 = (swz % gy) << 7, n0 = (swz / gy) << 7;

  const int wm = (wave >> 1) * 64, wn = (wave & 1) * 64;
  const f32x4 z4 = {0.f, 0.f, 0.f, 0.f};
  f32x4 acc[4][4];
#pragma unroll
  for (int i = 0; i < 4; ++i)
#pragma unroll
    for (int j = 0; j < 4; ++j) acc[i][j] = z4;

  const int srow = t >> 3;
  const int scb = (((t & 7) ^ ((t >> 3) & 7)) << 4);
  const char* Ab = (const char*)A;
  const char* Bb = (const char*)Bt;
  char* sAb = (char*)sA;
  char* sBb = (char*)sB;
  const long ldb2 = (long)K * 2;
  const int pc0 = (((lane >> 4) ^ (lane & 7)) << 4);

  for (int k0 = 0; k0 < K; k0 += 64) {
    __syncthreads();
#pragma unroll
    for (int i = 0; i < 4; ++i) {
      int row = i * 32 + srow;
      gl_lds16(Ab + (long)(m0 + row) * ldb2 + (long)k0 * 2 + scb,
               sAb + i * 4096 + wave * 1024);
      gl_lds16(Bb + (long)(n0 + row) * ldb2 + (long)k0 * 2 + scb,
               sBb + i * 4096 + wave * 1024);
    }
    __syncthreads();
#pragma unroll
    for (int kk = 0; kk < 2; ++kk) {
      const int kb = pc0 ^ (kk << 6);
      bf16x8 af[4], bfr[4];
#pragma unroll
      for (int f = 0; f < 4; ++f) {
        int ra = wm + f * 16 + (lane & 15);
        af[f] = *(const bf16x8*)(sAb + ra * 128 + kb);
        int rb = wn + f * 16 + (lane & 15);
        bfr[f] = *(const bf16x8*)(sBb + rb * 128 + kb);
      }
#pragma unroll
      for (int fm = 0; fm < 4; ++fm)
#pragma unroll
        for (int fn = 0; fn < 4; ++fn)
          acc[fm][fn] = __builtin_amdgcn_mfma_f32_16x16x32_bf16(af[fm], bfr[fn], acc[fm][fn], 0, 0, 0);
    }
  }
  const int rl = (lane >> 4) << 2;
  const int cl = lane & 15;
#pragma unroll
  for (int fm = 0; fm < 4; ++fm) {
#pragma unroll
    for (int fn = 0; fn < 4; ++fn) {
#pragma unroll
      for (int r = 0; r < 4; ++r) {
        int m = m0 + wm + fm * 16 + rl + r;
        int n = n0 + wn + fn * 16 + cl;
        float v = acc[fm][fn][r];
        if (EPI == 1) v += bias[n] + res[(long)m * N + n];
        if (EPI == 1) outf[(long)m * N + n] = v;
        else outb[(long)m * N + n] = f2bf(v);
      }
    }
  }
}

// ---------- 256^2 8-phase GEMM (BK=64, 2 dbuf, counted vmcnt) ----------
// EPI 0: bf16 out. EPI 2: bf16 out = gelu(acc+bias). EPI 3: f32 out = acc+bias.
template <int EPI>
__global__ __launch_bounds__(512, 1) void gemm256(const unsigned short* __restrict__ A,
                                                  const unsigned short* __restrict__ Bt,
                                                  float* __restrict__ outf,
                                                  unsigned short* __restrict__ outb,
                                                  const float* __restrict__ bias,
                                                  int M, int N, int K) {
  __shared__ __align__(16) char smem[131072];  // 2 bufs x (A 32K + B 32K)
  const int t = threadIdx.x;
  const int wave = t >> 6, lane = t & 63;

  const int gx = gridDim.x, gy = gridDim.y;
  const int nwg = gx * gy;
  const int bid = blockIdx.y * gx + blockIdx.x;
  const int qd = nwg >> 3, rd = nwg & 7;
  const int xcd = bid & 7, off = bid >> 3;
  const int swz = (xcd < rd ? xcd * (qd + 1) : rd * (qd + 1) + (xcd - rd) * qd) + off;
  const int m0 = (swz % gy) << 8, n0 = (swz / gy) << 8;

  const int wm = (wave >> 2) << 7;  // 0 / 128
  const int wn = (wave & 3) << 6;   // 0,64,128,192
  const int KT2 = K >> 7;           // iterations; 2 K-tiles (BK=64) each

  const f32x4 z4 = {0.f, 0.f, 0.f, 0.f};
  f32x4 acc[8][4];
#pragma unroll
  for (int i = 0; i < 8; ++i)
#pragma unroll
    for (int j = 0; j < 4; ++j) acc[i][j] = z4;

  const int sck = (((t & 7) ^ ((t >> 3) & 7)) << 4);   // pre-swizzled src chunk bytes
  const long ldb = (long)K * 2;
  const char* Abase = (const char*)A + (long)(m0 + (t >> 3)) * ldb + sck;
  const char* Bbase = (const char*)Bt + (long)(n0 + (t >> 3)) * ldb + sck;

#define STG(base, tt, h, boff)                                              \
  { char* d = smem + (((tt) & 1) << 16) + (boff) + ((h) << 14) + wave * 1024; \
    const char* s = (base) + (long)((h) * 128) * ldb + ((long)(tt) << 7);     \
    gl_lds16(s, d); gl_lds16(s + (ldb << 6), d + 8192); }

  STG(Bbase, 0, 0, 32768); STG(Bbase, 0, 1, 32768);
  STG(Abase, 0, 0, 0);     STG(Abase, 0, 1, 0);
  STG(Bbase, 1, 0, 32768); STG(Bbase, 1, 1, 32768);
  STG(Abase, 1, 0, 0);
  asm volatile("s_waitcnt vmcnt(6)" ::: "memory");
  __builtin_amdgcn_sched_barrier(0);
  __builtin_amdgcn_s_barrier();

  const int la15 = lane & 15;
  const int pck0 = (((lane >> 4) ^ (la15 & 7)) << 4);  // phys chunk, kh=0
  const int pck1 = pck0 ^ 64;                          // kh=1

#define DS_A(q)                                                              \
  a00 = *(const bf16x8*)(bA + (wm + ((q) * 2) * 16 + la15) * 128 + pck0);    \
  a01 = *(const bf16x8*)(bA + (wm + ((q) * 2) * 16 + la15) * 128 + pck1);    \
  a10 = *(const bf16x8*)(bA + (wm + ((q) * 2 + 1) * 16 + la15) * 128 + pck0);\
  a11 = *(const bf16x8*)(bA + (wm + ((q) * 2 + 1) * 16 + la15) * 128 + pck1);

#define MFMA_Q(q)                                                                              \
  __builtin_amdgcn_s_setprio(1);                                                               \
  { _Pragma("unroll") for (int nf = 0; nf < 4; ++nf) {                                         \
      acc[(q)*2][nf]     = __builtin_amdgcn_mfma_f32_16x16x32_bf16(a00, bfr[nf][0], acc[(q)*2][nf], 0, 0, 0);     \
      acc[(q)*2][nf]     = __builtin_amdgcn_mfma_f32_16x16x32_bf16(a01, bfr[nf][1], acc[(q)*2][nf], 0, 0, 0);     \
      acc[(q)*2 + 1][nf] = __builtin_amdgcn_mfma_f32_16x16x32_bf16(a10, bfr[nf][0], acc[(q)*2 + 1][nf], 0, 0, 0); \
      acc[(q)*2 + 1][nf] = __builtin_amdgcn_mfma_f32_16x16x32_bf16(a11, bfr[nf][1], acc[(q)*2 + 1][nf], 0, 0, 0); \
  } }                                                                                          \
  __builtin_amdgcn_s_setprio(0);

#define BAR_LGKM()                                    \
  __builtin_amdgcn_s_barrier();                       \
  asm volatile("s_waitcnt lgkmcnt(0)" ::: "memory");  \
  __builtin_amdgcn_sched_barrier(0);

  for (int it = 0; it < KT2; ++it) {
    const bool more = (it + 1 < KT2);
#pragma unroll
    for (int g = 0; g < 2; ++g) {
      const int tt = 2 * it + g;
      const char* bA = smem + ((tt & 1) << 16);
      const char* bB = bA + 32768;
      bf16x8 bfr[4][2], a00, a01, a10, a11;

#pragma unroll
      for (int nf = 0; nf < 4; ++nf) {
        bfr[nf][0] = *(const bf16x8*)(bB + (wn + nf * 16 + la15) * 128 + pck0);
        bfr[nf][1] = *(const bf16x8*)(bB + (wn + nf * 16 + la15) * 128 + pck1);
      }
      DS_A(0);
      if (g == 0) { STG(Abase, tt + 1, 1, 0); }
      else if (more) { STG(Abase, tt + 1, 1, 0); }
      asm volatile("s_waitcnt lgkmcnt(8)" ::: "memory");
      BAR_LGKM();
      MFMA_Q(0);
      __builtin_amdgcn_s_barrier();

      DS_A(1);
      if (more) { STG(Bbase, tt + 2, 0, 32768); }
      BAR_LGKM();
      MFMA_Q(1);
      __builtin_amdgcn_s_barrier();

      DS_A(2);
      if (more) { STG(Bbase, tt + 2, 1, 32768); }
      BAR_LGKM();
      MFMA_Q(2);
      __builtin_amdgcn_s_barrier();

      DS_A(3);
      if (more) { STG(Abase, tt + 2, 0, 0); }
      BAR_LGKM();
      MFMA_Q(3);
      if (g == 0) {
        if (more) { asm volatile("s_waitcnt vmcnt(6)" ::: "memory"); }
        else      { asm volatile("s_waitcnt vmcnt(0)" ::: "memory"); }
        __builtin_amdgcn_sched_barrier(0);
      } else if (more) {
        asm volatile("s_waitcnt vmcnt(6)" ::: "memory");
        __builtin_amdgcn_sched_barrier(0);
      }
      __builtin_amdgcn_s_barrier();
    }
  }
#undef STG
#undef DS_A
#undef MFMA_Q
#undef BAR_LGKM

  // epilogue (fn innermost so each 128B line is written contiguously)
  const int rl = (lane >> 4) << 2;
#pragma unroll
  for (int fm = 0; fm < 8; ++fm) {
#pragma unroll
    for (int r = 0; r < 4; ++r) {
      int m = m0 + wm + fm * 16 + rl + r;
#pragma unroll
      for (int fn = 0; fn < 4; ++fn) {
        int n = n0 + wn + fn * 16 + la15;
        float v = acc[fm][fn][r];
        if (EPI == 2 || EPI == 3) v += bias[n];
        if (EPI == 2) v = 0.5f * v * (1.f + erff(v * 0.70710678118f));
        if (EPI == 3) outf[(long)m * N + n] = v;
        else outb[(long)m * N + n] = f2bf(v);
      }
    }
  }
}

// ---------- causal flash attention, paired q-tiles for uniform block cost ----------
__global__ __launch_bounds__(256) void attn_k(const unsigned short* __restrict__ qkv,
                                              unsigned short* __restrict__ o) {
  const int pi = blockIdx.x;          // 0..7
  const int pair = blockIdx.y;
  const int b = pair >> 4, h = pair & 15;
  const int t = threadIdx.x, wave = t >> 6, lane = t & 63;
  __shared__ __align__(16) unsigned short sQ[64 * 64];
  __shared__ __align__(16) unsigned short sK[2][64 * 64];
  __shared__ __align__(16) unsigned short sV[2][64 * 64];   // transposed [e][j]
  __shared__ __align__(16) unsigned short sP[4][16 * 64];

  const long baseq = (long)b * (1024 * 3072) + (long)h * 64;
  const unsigned short* qp = qkv + baseq;
  const unsigned short* kp = qkv + baseq + 1024;
  const unsigned short* vp = qkv + baseq + 2048;
  const long baseo = (long)b * (1024 * 1024) + (long)h * 64;

  const int row0 = t >> 3, c0 = t & 7;
  const int row1 = (t + 256) >> 3, c1 = t & 7;
  const int qoff0 = ((c0 ^ (row0 & 7)) << 3);
  const int qoff1 = ((c1 ^ (row1 & 7)) << 3);

  const int qrow = wave * 16 + (lane & 15);
  const int qswz0 = ((lane >> 4) << 4) ^ ((qrow & 7) << 4);
  const int prow = lane & 15;
  const f32x4 z4 = {0.f, 0.f, 0.f, 0.f};

  for (int half = 0; half < 2; ++half) {
    const int qt = half ? (15 - pi) : pi;
    __syncthreads();   // protect LDS reuse across halves

    gl_lds16(qp + (long)(qt * 64 + row0) * 3072 + qoff0, (char*)sQ + wave * 1024);
    gl_lds16(qp + (long)(qt * 64 + row1) * 3072 + qoff1, (char*)sQ + 4096 + wave * 1024);
    gl_lds16(kp + (long)(0 + row0) * 3072 + qoff0, (char*)sK[0] + wave * 1024);
    gl_lds16(kp + (long)(0 + row1) * 3072 + qoff1, (char*)sK[0] + 4096 + wave * 1024);
    bf16x8 vr0 = *(const bf16x8*)(vp + (long)row0 * 3072 + (c0 << 3));
    bf16x8 vr1 = *(const bf16x8*)(vp + (long)row1 * 3072 + (c1 << 3));
    {
      char* vb = (char*)sV[0];
#pragma unroll
      for (int j = 0; j < 8; ++j) {
        int e0 = (c0 << 3) + j, e1 = (c1 << 3) + j;
        *(unsigned short*)(vb + e0 * 128 + ((row0 * 2) ^ ((e0 & 7) << 4))) = (unsigned short)vr0[j];
        *(unsigned short*)(vb + e1 * 128 + ((row1 * 2) ^ ((e1 & 7) << 4))) = (unsigned short)vr1[j];
      }
    }
    __syncthreads();

    float lst[4] = {0.f, 0.f, 0.f, 0.f};
    f32x4 oacc[4];
#pragma unroll
    for (int eb = 0; eb < 4; ++eb) oacc[eb] = z4;

    for (int kt = 0; kt <= qt; ++kt) {
      const int cur = kt & 1;

      bf16x8 aq[2];
#pragma unroll
      for (int kk = 0; kk < 2; ++kk)
        aq[kk] = *(const bf16x8*)((char*)sQ + qrow * 128 + ((kk << 6) ^ qswz0));
      f32x4 sf[4];
#pragma unroll
      for (int cb = 0; cb < 4; ++cb) {
        f32x4 s = z4;
        int kr = cb * 16 + (lane & 15);
        int kswz = ((kr & 7) << 4);
#pragma unroll
        for (int kk = 0; kk < 2; ++kk) {
          int e0 = (kk * 32 + ((lane >> 4) << 3)) * 2;
          bf16x8 bk = *(const bf16x8*)((char*)sK[cur] + kr * 128 + (e0 ^ kswz));
          s = __builtin_amdgcn_mfma_f32_16x16x32_bf16(aq[kk], bk, s, 0, 0, 0);
        }
        sf[cb] = s;
      }

      if (kt < qt) {
        const int nxt = cur ^ 1;
        const long krb = (long)((kt + 1) * 64);
        gl_lds16(kp + (krb + row0) * 3072 + qoff0, (char*)sK[nxt] + wave * 1024);
        gl_lds16(kp + (krb + row1) * 3072 + qoff1, (char*)sK[nxt] + 4096 + wave * 1024);
        vr0 = *(const bf16x8*)(vp + (krb + row0) * 3072 + (c0 << 3));
        vr1 = *(const bf16x8*)(vp + (krb + row1) * 3072 + (c1 << 3));
      }

      const bool diag = (kt == qt);
      unsigned short* pb = sP[wave];
#pragma unroll
      for (int r = 0; r < 4; ++r) {
        int qg = wave * 16 + ((lane >> 4) << 2) + r;
        int lr = ((lane >> 4) << 2) + r;
        float rs = 0.f;
#pragma unroll
        for (int cb = 0; cb < 4; ++cb) {
          float p;
          if (diag) {
            int kg = cb * 16 + (lane & 15);
            p = (kg > qg) ? 0.f : __expf(sf[cb][r] * 0.125f);
          } else {
            p = __expf(sf[cb][r] * 0.125f);
          }
          rs += p;
          int col = cb * 16 + (lane & 15);
          *(unsigned short*)((char*)pb + lr * 128 + ((col * 2) ^ ((lr & 7) << 4))) = f2bf(p);
        }
        lst[r] += rs;
      }

      bf16x8 ap[2];
#pragma unroll
      for (int kk = 0; kk < 2; ++kk) {
        int j0 = (kk * 32 + ((lane >> 4) << 3)) * 2;
        ap[kk] = *(const bf16x8*)((char*)pb + prow * 128 + (j0 ^ ((prow & 7) << 4)));
      }
#pragma unroll
      for (int eb = 0; eb < 4; ++eb) {
        int er = eb * 16 + (lane & 15);
        int eswz = ((er & 7) << 4);
#pragma unroll
        for (int kk = 0; kk < 2; ++kk) {
          int j0 = (kk * 32 + ((lane >> 4) << 3)) * 2;
          bf16x8 bv = *(const bf16x8*)((char*)sV[cur] + er * 128 + (j0 ^ eswz));
          oacc[eb] = __builtin_amdgcn_mfma_f32_16x16x32_bf16(ap[kk], bv, oacc[eb], 0, 0, 0);
        }
      }

      if (kt < qt) {
        char* vb = (char*)sV[cur ^ 1];
#pragma unroll
        for (int j = 0; j < 8; ++j) {
          int e0 = (c0 << 3) + j, e1 = (c1 << 3) + j;
          *(unsigned short*)(vb + e0 * 128 + ((row0 * 2) ^ ((e0 & 7) << 4))) = (unsigned short)vr0[j];
          *(unsigned short*)(vb + e1 * 128 + ((row1 * 2) ^ ((e1 & 7) << 4))) = (unsigned short)vr1[j];
        }
        __syncthreads();
      }
    }

#pragma unroll
    for (int r = 0; r < 4; ++r) {
      float l = lst[r];
#pragma unroll
      for (int d = 1; d < 16; d <<= 1) l += __shfl_xor(l, d, 64);
      float inv = 1.f / l;
      int qg = qt * 64 + wave * 16 + ((lane >> 4) << 2) + r;
#pragma unroll
      for (int eb = 0; eb < 4; ++eb) {
        int e = eb * 16 + (lane & 15);
        o[baseo + (long)qg * 1024 + e] = f2bf(oacc[eb][r] * inv);
      }
    }
  }
}

// ---------- host launch ----------
extern "C" void kernel_launch(void* const* d_in, const int* in_sizes, int n_in,
                              void* d_out, int out_size, void* d_ws, size_t ws_size,
                              hipStream_t stream) {
  const int* idx = (const int*)d_in[0];
  const float* tok = (const float*)d_in[1];
  const float* pos = (const float*)d_in[2];
  const float* Wq = (const float*)d_in[3];
  const float* Wk = (const float*)d_in[4];
  const float* Wv = (const float*)d_in[5];
  const float* Wo = (const float*)d_in[6];
  const float* bo = (const float*)d_in[7];
  const float* ln1g = (const float*)d_in[8];
  const float* ln1b = (const float*)d_in[9];
  const float* ln2g = (const float*)d_in[10];
  const float* ln2b = (const float*)d_in[11];
  const float* W1 = (const float*)d_in[12];
  const float* b1 = (const float*)d_in[13];
  const float* W2 = (const float*)d_in[14];
  const float* b2 = (const float*)d_in[15];
  const float* lnfg = (const float*)d_in[16];
  const float* lnfb = (const float*)d_in[17];
  const float* Wh = (const float*)d_in[18];
  const float* bh = (const float*)d_in[19];

  char* ws = (char*)d_ws;
  const long Mi = 1024 * 1024;
  float* x = (float*)ws;
  unsigned short* xn = (unsigned short*)(ws + 16 * Mi);
  unsigned short* qkv = (unsigned short*)(ws + 24 * Mi);
  unsigned short* ob = (unsigned short*)(ws + 48 * Mi);
  unsigned short* hmid = (unsigned short*)(ws + 24 * Mi);
  unsigned short* wqkvT = (unsigned short*)(ws + 56 * Mi);
  unsigned short* whT = (unsigned short*)(ws + 56 * Mi);   // alias (post-loop)

  // big-ws path: all-layer transposed weights; small path: per-layer buffers
  const bool bigws = (ws_size >= (size_t)250 * 1024 * 1024);
  unsigned short* wotA = (unsigned short*)(ws + 104 * Mi);  // 8 x 2 MiB  = 16 MiB
  unsigned short* w1tA = (unsigned short*)(ws + 120 * Mi);  // 8 x 8 MiB  = 64 MiB
  unsigned short* w2tA = (unsigned short*)(ws + 184 * Mi);  // 8 x 8 MiB  = 64 MiB
  unsigned short* wot1 = (unsigned short*)(ws + 104 * Mi);  // small path (per-layer)
  unsigned short* w1t1 = (unsigned short*)(ws + 106 * Mi);
  unsigned short* w2t1 = (unsigned short*)(ws + 114 * Mi);

  dim3 blk256(256), blk512(512), blkT(32, 8);

  embed_k<<<4096, blk256, 0, stream>>>(idx, tok, pos, x);
  tr_qkv_k<<<dim3(2, 32, 384), blkT, 0, stream>>>(Wq, Wk, Wv, wqkvT);
  if (bigws) {
    tr_k<<<dim3(32, 32, 8), blkT, 0, stream>>>(Wo, wotA, 1024, 1024, 1048576, 1048576);
    tr_k<<<dim3(128, 32, 8), blkT, 0, stream>>>(W1, w1tA, 1024, 4096, 4194304, 4194304);
    tr_k<<<dim3(32, 128, 8), blkT, 0, stream>>>(W2, w2tA, 4096, 1024, 4194304, 4194304);
  }

  for (int l = 0; l < 8; ++l) {
    const float* bo_l = bo + (long)l * 1024;
    const float* b1_l = b1 + (long)l * 4096;
    const float* b2_l = b2 + (long)l * 1024;
    const unsigned short* wqkv_l = wqkvT + (long)l * (3072 * 1024);

    const unsigned short* wot_l;
    const unsigned short* w1t_l;
    const unsigned short* w2t_l;
    if (bigws) {
      wot_l = wotA + (long)l * 1048576;
      w1t_l = w1tA + (long)l * 4194304;
      w2t_l = w2tA + (long)l * 4194304;
    } else {
      tr_k<<<dim3(32, 32, 1), blkT, 0, stream>>>(Wo + (long)l * 1048576, wot1, 1024, 1024, 0, 0);
      tr_k<<<dim3(128, 32, 1), blkT, 0, stream>>>(W1 + (long)l * 4194304, w1t1, 1024, 4096, 0, 0);
      tr_k<<<dim3(32, 128, 1), blkT, 0, stream>>>(W2 + (long)l * 4194304, w2t1, 4096, 1024, 0, 0);
      wot_l = wot1; w1t_l = w1t1; w2t_l = w2t1;
    }

    ln_k<<<4096, blk256, 0, stream>>>(x, ln1g + l * 1024, ln1b + l * 1024, xn);

    // fused QKV projection: 256^2 8-phase (N=3072 -> 192 blocks; beats 128^2 here)
    gemm256<0><<<dim3(12, 16), blk512, 0, stream>>>(xn, wqkv_l, nullptr, qkv, nullptr, 4096, 3072, 1024);

    attn_k<<<dim3(8, 64), blk256, 0, stream>>>(qkv, ob);

    gemm_bt<1><<<dim3(8, 32), blk256, 0, stream>>>(ob, wot_l, x, nullptr, bo_l, x, 4096, 1024, 1024);

    ln_k<<<4096, blk256, 0, stream>>>(x, ln2g + l * 1024, ln2b + l * 1024, xn);

    gemm256<2><<<dim3(16, 16), blk512, 0, stream>>>(xn, w1t_l, nullptr, hmid, b1_l, 4096, 4096, 1024);
    gemm_bt<1><<<dim3(8, 32), blk256, 0, stream>>>(hmid, w2t_l, x, nullptr, b2_l, x, 4096, 1024, 4096);
  }

  ln_k<<<4096, blk256, 0, stream>>>(x, lnfg, lnfb, xn);
  tr_k<<<dim3(1000, 32, 1), blkT, 0, stream>>>(Wh, whT, 1024, 32000, 0, 0);
  gemm256<3><<<dim3(125, 16), blk512, 0, stream>>>(xn, whT, (float*)d_out, nullptr, bh, 4096, 32000, 1024);
}

// Round 14
// 2326.724 us; speedup vs baseline: 1.0637x; 1.0214x over previous
//
#include <hip/hip_runtime.h>
#include <hip/hip_bf16.h>

// ---------- common ----------
typedef short bf16x8 __attribute__((ext_vector_type(8)));
typedef float f32x4 __attribute__((ext_vector_type(4)));

__device__ __forceinline__ unsigned short f2bf(float f) {
  union { float f; unsigned u; } un; un.f = f;
  unsigned r = un.u + 0x7fffu + ((un.u >> 16) & 1u);
  return (unsigned short)(r >> 16);
}

__device__ __forceinline__ void gl_lds16(const void* g, void* l) {
  __builtin_amdgcn_global_load_lds(
      (const __attribute__((address_space(1))) void*)g,
      (__attribute__((address_space(3))) void*)l, 16, 0, 0);
}

// XCD-aware bijective swizzle + 2D band (MB=4): consecutive blocks within an
// XCD cover a 4m x 8n patch -> A/B working sets fit L2 (m201 locality).
__device__ __forceinline__ void tile_map(int bid, int gx, int gy, int tshift,
                                         int& m0, int& n0) {
  const int nwg = gx * gy;
  const int qd = nwg >> 3, rd = nwg & 7;
  const int xcd = bid & 7, off = bid >> 3;
  const int swz = (xcd < rd ? xcd * (qd + 1) : rd * (qd + 1) + (xcd - rd) * qd) + off;
  const int mb = swz & 3;
  const int r = swz >> 2;
  const int nn = r % gx;
  const int band = r / gx;
  m0 = ((band << 2) + mb) << tshift;
  n0 = nn << tshift;
}

// ---------- embedding ----------
__global__ __launch_bounds__(256) void embed_k(const int* __restrict__ idx,
                                               const float* __restrict__ tok,
                                               const float* __restrict__ pos,
                                               float* __restrict__ x) {
  int m = blockIdx.x, t = threadIdx.x;
  int tk = idx[m];
  int tp = m & 1023;
  f32x4 a = __builtin_nontemporal_load((const f32x4*)(tok + (long)tk * 1024) + t);
  f32x4 p = ((const f32x4*)(pos + (long)tp * 1024))[t];
  a += p;
  ((f32x4*)(x + (long)m * 1024))[t] = a;
}

// ---------- layernorm: fp32 x -> bf16 out ----------
__global__ __launch_bounds__(256) void ln_k(const float* __restrict__ x,
                                            const float* __restrict__ g,
                                            const float* __restrict__ b,
                                            unsigned short* __restrict__ out) {
  int row = blockIdx.x, t = threadIdx.x;
  float4 v = ((const float4*)(x + (long)row * 1024))[t];
  float s = v.x + v.y + v.z + v.w;
  float ss = v.x * v.x + v.y * v.y + v.z * v.z + v.w * v.w;
#pragma unroll
  for (int d = 32; d; d >>= 1) { s += __shfl_xor(s, d, 64); ss += __shfl_xor(ss, d, 64); }
  __shared__ float red[8];
  int wave = t >> 6, lane = t & 63;
  if (lane == 0) { red[wave] = s; red[wave + 4] = ss; }
  __syncthreads();
  s = red[0] + red[1] + red[2] + red[3];
  ss = red[4] + red[5] + red[6] + red[7];
  float mu = s * (1.f / 1024.f);
  float var = ss * (1.f / 1024.f) - mu * mu;
  float rstd = rsqrtf(var + 1e-5f);
  float4 gv = ((const float4*)g)[t];
  float4 bv = ((const float4*)b)[t];
  ushort4 o;
  o.x = f2bf((v.x - mu) * rstd * gv.x + bv.x);
  o.y = f2bf((v.y - mu) * rstd * gv.y + bv.y);
  o.z = f2bf((v.z - mu) * rstd * gv.z + bv.z);
  o.w = f2bf((v.w - mu) * rstd * gv.w + bv.w);
  ((ushort4*)(out + (long)row * 1024))[t] = o;
}

// ---------- generic batched transpose fp32[R,C] -> bf16[C,R] (NT reads) ----------
__global__ __launch_bounds__(256) void tr_k(const float* __restrict__ in,
                                            unsigned short* __restrict__ out,
                                            int R, int C, long inStride, long outStride) {
  __shared__ float tile[32][33];
  int batch = blockIdx.z;
  int c0 = blockIdx.x * 32, r0 = blockIdx.y * 32;
  const float* ip = in + (long)batch * inStride;
  unsigned short* op = out + (long)batch * outStride;
  int tx = threadIdx.x, ty = threadIdx.y; // (32,8)
#pragma unroll
  for (int i = 0; i < 4; ++i)
    tile[ty + i * 8][tx] = __builtin_nontemporal_load(ip + (long)(r0 + ty + i * 8) * C + c0 + tx);
  __syncthreads();
#pragma unroll
  for (int i = 0; i < 4; ++i)
    op[(long)(c0 + ty + i * 8) * R + r0 + tx] = f2bf(tile[tx][ty + i * 8]);
}

// ---------- all-layer QKV weight transpose (NT reads) ----------
__global__ __launch_bounds__(256) void tr_qkv_k(const float* __restrict__ wq,
                                                const float* __restrict__ wk,
                                                const float* __restrict__ wv,
                                                unsigned short* __restrict__ out) {
  __shared__ float tile[32][33];
  int z = blockIdx.z;                 // 0..383
  int tsel = z >> 7, rem = z & 127;
  int l = rem >> 4, h = rem & 15;
  const float* ip = (tsel == 0 ? wq : tsel == 1 ? wk : wv) + (long)rem * 65536;
  unsigned short* op = out + (long)l * (3072 * 1024) + (long)tsel * (1024 * 1024) +
                       (long)h * 65536;
  int c0 = blockIdx.x * 32, r0 = blockIdx.y * 32;
  int tx = threadIdx.x, ty = threadIdx.y;
#pragma unroll
  for (int i = 0; i < 4; ++i)
    tile[ty + i * 8][tx] = __builtin_nontemporal_load(ip + (long)(r0 + ty + i * 8) * 64 + c0 + tx);
  __syncthreads();
#pragma unroll
  for (int i = 0; i < 4; ++i)
    op[(long)(c0 + ty + i * 8) * 1024 + r0 + tx] = f2bf(tile[tx][ty + i * 8]);
}

// ---------- 128^2 GEMM (N=1024 shapes: high occupancy) ----------
// EPI 1: f32 out = acc+bias+res.
template <int EPI>
__global__ __launch_bounds__(256) void gemm_bt(const unsigned short* __restrict__ A,
                                               const unsigned short* __restrict__ Bt,
                                               float* __restrict__ outf,
                                               unsigned short* __restrict__ outb,
                                               const float* __restrict__ bias,
                                               const float* __restrict__ res,
                                               int M, int N, int K) {
  __shared__ __align__(16) unsigned short sA[128 * 64];
  __shared__ __align__(16) unsigned short sB[128 * 64];
  const int t = threadIdx.x;
  const int wave = t >> 6, lane = t & 63;

  int m0, n0;
  tile_map(blockIdx.y * gridDim.x + blockIdx.x, gridDim.x, gridDim.y, 7, m0, n0);

  const int wm = (wave >> 1) * 64, wn = (wave & 1) * 64;
  const f32x4 z4 = {0.f, 0.f, 0.f, 0.f};
  f32x4 acc[4][4];
#pragma unroll
  for (int i = 0; i < 4; ++i)
#pragma unroll
    for (int j = 0; j < 4; ++j) acc[i][j] = z4;

  const int srow = t >> 3;
  const int scb = (((t & 7) ^ ((t >> 3) & 7)) << 4);
  const char* Ab = (const char*)A;
  const char* Bb = (const char*)Bt;
  char* sAb = (char*)sA;
  char* sBb = (char*)sB;
  const long ldb2 = (long)K * 2;
  const int pc0 = (((lane >> 4) ^ (lane & 7)) << 4);

  for (int k0 = 0; k0 < K; k0 += 64) {
    __syncthreads();
#pragma unroll
    for (int i = 0; i < 4; ++i) {
      int row = i * 32 + srow;
      gl_lds16(Ab + (long)(m0 + row) * ldb2 + (long)k0 * 2 + scb,
               sAb + i * 4096 + wave * 1024);
      gl_lds16(Bb + (long)(n0 + row) * ldb2 + (long)k0 * 2 + scb,
               sBb + i * 4096 + wave * 1024);
    }
    __syncthreads();
#pragma unroll
    for (int kk = 0; kk < 2; ++kk) {
      const int kb = pc0 ^ (kk << 6);
      bf16x8 af[4], bfr[4];
#pragma unroll
      for (int f = 0; f < 4; ++f) {
        int ra = wm + f * 16 + (lane & 15);
        af[f] = *(const bf16x8*)(sAb + ra * 128 + kb);
        int rb = wn + f * 16 + (lane & 15);
        bfr[f] = *(const bf16x8*)(sBb + rb * 128 + kb);
      }
#pragma unroll
      for (int fm = 0; fm < 4; ++fm)
#pragma unroll
        for (int fn = 0; fn < 4; ++fn)
          acc[fm][fn] = __builtin_amdgcn_mfma_f32_16x16x32_bf16(af[fm], bfr[fn], acc[fm][fn], 0, 0, 0);
    }
  }
  const int rl = (lane >> 4) << 2;
  const int cl = lane & 15;
#pragma unroll
  for (int fm = 0; fm < 4; ++fm) {
#pragma unroll
    for (int fn = 0; fn < 4; ++fn) {
#pragma unroll
      for (int r = 0; r < 4; ++r) {
        int m = m0 + wm + fm * 16 + rl + r;
        int n = n0 + wn + fn * 16 + cl;
        float v = acc[fm][fn][r];
        if (EPI == 1) v += bias[n] + res[(long)m * N + n];
        if (EPI == 1) outf[(long)m * N + n] = v;
        else outb[(long)m * N + n] = f2bf(v);
      }
    }
  }
}

// ---------- 256^2 8-phase GEMM (BK=64, 2 dbuf, counted vmcnt) ----------
// EPI 0: bf16 out. EPI 2: bf16 out = gelu(acc+bias). EPI 3: f32 out = acc+bias.
template <int EPI>
__global__ __launch_bounds__(512, 1) void gemm256(const unsigned short* __restrict__ A,
                                                  const unsigned short* __restrict__ Bt,
                                                  float* __restrict__ outf,
                                                  unsigned short* __restrict__ outb,
                                                  const float* __restrict__ bias,
                                                  int M, int N, int K) {
  __shared__ __align__(16) char smem[131072];  // 2 bufs x (A 32K + B 32K)
  const int t = threadIdx.x;
  const int wave = t >> 6, lane = t & 63;

  int m0, n0;
  tile_map(blockIdx.y * gridDim.x + blockIdx.x, gridDim.x, gridDim.y, 8, m0, n0);

  const int wm = (wave >> 2) << 7;  // 0 / 128
  const int wn = (wave & 3) << 6;   // 0,64,128,192
  const int KT2 = K >> 7;           // iterations; 2 K-tiles (BK=64) each

  const f32x4 z4 = {0.f, 0.f, 0.f, 0.f};
  f32x4 acc[8][4];
#pragma unroll
  for (int i = 0; i < 8; ++i)
#pragma unroll
    for (int j = 0; j < 4; ++j) acc[i][j] = z4;

  const int sck = (((t & 7) ^ ((t >> 3) & 7)) << 4);   // pre-swizzled src chunk bytes
  const long ldb = (long)K * 2;
  const char* Abase = (const char*)A + (long)(m0 + (t >> 3)) * ldb + sck;
  const char* Bbase = (const char*)Bt + (long)(n0 + (t >> 3)) * ldb + sck;

#define STG(base, tt, h, boff)                                              \
  { char* d = smem + (((tt) & 1) << 16) + (boff) + ((h) << 14) + wave * 1024; \
    const char* s = (base) + (long)((h) * 128) * ldb + ((long)(tt) << 7);     \
    gl_lds16(s, d); gl_lds16(s + (ldb << 6), d + 8192); }

  STG(Bbase, 0, 0, 32768); STG(Bbase, 0, 1, 32768);
  STG(Abase, 0, 0, 0);     STG(Abase, 0, 1, 0);
  STG(Bbase, 1, 0, 32768); STG(Bbase, 1, 1, 32768);
  STG(Abase, 1, 0, 0);
  asm volatile("s_waitcnt vmcnt(6)" ::: "memory");
  __builtin_amdgcn_sched_barrier(0);
  __builtin_amdgcn_s_barrier();

  const int la15 = lane & 15;
  const int pck0 = (((lane >> 4) ^ (la15 & 7)) << 4);  // phys chunk, kh=0
  const int pck1 = pck0 ^ 64;                          // kh=1

#define DS_A(q)                                                              \
  a00 = *(const bf16x8*)(bA + (wm + ((q) * 2) * 16 + la15) * 128 + pck0);    \
  a01 = *(const bf16x8*)(bA + (wm + ((q) * 2) * 16 + la15) * 128 + pck1);    \
  a10 = *(const bf16x8*)(bA + (wm + ((q) * 2 + 1) * 16 + la15) * 128 + pck0);\
  a11 = *(const bf16x8*)(bA + (wm + ((q) * 2 + 1) * 16 + la15) * 128 + pck1);

#define MFMA_Q(q)                                                                              \
  __builtin_amdgcn_s_setprio(1);                                                               \
  { _Pragma("unroll") for (int nf = 0; nf < 4; ++nf) {                                         \
      acc[(q)*2][nf]     = __builtin_amdgcn_mfma_f32_16x16x32_bf16(a00, bfr[nf][0], acc[(q)*2][nf], 0, 0, 0);     \
      acc[(q)*2][nf]     = __builtin_amdgcn_mfma_f32_16x16x32_bf16(a01, bfr[nf][1], acc[(q)*2][nf], 0, 0, 0);     \
      acc[(q)*2 + 1][nf] = __builtin_amdgcn_mfma_f32_16x16x32_bf16(a10, bfr[nf][0], acc[(q)*2 + 1][nf], 0, 0, 0); \
      acc[(q)*2 + 1][nf] = __builtin_amdgcn_mfma_f32_16x16x32_bf16(a11, bfr[nf][1], acc[(q)*2 + 1][nf], 0, 0, 0); \
  } }                                                                                          \
  __builtin_amdgcn_s_setprio(0);

#define BAR_LGKM()                                    \
  __builtin_amdgcn_s_barrier();                       \
  asm volatile("s_waitcnt lgkmcnt(0)" ::: "memory");  \
  __builtin_amdgcn_sched_barrier(0);

  for (int it = 0; it < KT2; ++it) {
    const bool more = (it + 1 < KT2);
#pragma unroll
    for (int g = 0; g < 2; ++g) {
      const int tt = 2 * it + g;
      const char* bA = smem + ((tt & 1) << 16);
      const char* bB = bA + 32768;
      bf16x8 bfr[4][2], a00, a01, a10, a11;

#pragma unroll
      for (int nf = 0; nf < 4; ++nf) {
        bfr[nf][0] = *(const bf16x8*)(bB + (wn + nf * 16 + la15) * 128 + pck0);
        bfr[nf][1] = *(const bf16x8*)(bB + (wn + nf * 16 + la15) * 128 + pck1);
      }
      DS_A(0);
      if (g == 0) { STG(Abase, tt + 1, 1, 0); }
      else if (more) { STG(Abase, tt + 1, 1, 0); }
      asm volatile("s_waitcnt lgkmcnt(8)" ::: "memory");
      BAR_LGKM();
      MFMA_Q(0);
      __builtin_amdgcn_s_barrier();

      DS_A(1);
      if (more) { STG(Bbase, tt + 2, 0, 32768); }
      BAR_LGKM();
      MFMA_Q(1);
      __builtin_amdgcn_s_barrier();

      DS_A(2);
      if (more) { STG(Bbase, tt + 2, 1, 32768); }
      BAR_LGKM();
      MFMA_Q(2);
      __builtin_amdgcn_s_barrier();

      DS_A(3);
      if (more) { STG(Abase, tt + 2, 0, 0); }
      BAR_LGKM();
      MFMA_Q(3);
      if (g == 0) {
        if (more) { asm volatile("s_waitcnt vmcnt(6)" ::: "memory"); }
        else      { asm volatile("s_waitcnt vmcnt(0)" ::: "memory"); }
        __builtin_amdgcn_sched_barrier(0);
      } else if (more) {
        asm volatile("s_waitcnt vmcnt(6)" ::: "memory");
        __builtin_amdgcn_sched_barrier(0);
      }
      __builtin_amdgcn_s_barrier();
    }
  }
#undef STG
#undef DS_A
#undef MFMA_Q
#undef BAR_LGKM

  // epilogue (fn innermost so each 128B line is written contiguously)
  const int rl = (lane >> 4) << 2;
#pragma unroll
  for (int fm = 0; fm < 8; ++fm) {
#pragma unroll
    for (int r = 0; r < 4; ++r) {
      int m = m0 + wm + fm * 16 + rl + r;
#pragma unroll
      for (int fn = 0; fn < 4; ++fn) {
        int n = n0 + wn + fn * 16 + la15;
        float v = acc[fm][fn][r];
        if (EPI == 2 || EPI == 3) v += bias[n];
        if (EPI == 2) v = 0.5f * v * (1.f + erff(v * 0.70710678118f));
        if (EPI == 3) outf[(long)m * N + n] = v;
        else outb[(long)m * N + n] = f2bf(v);
      }
    }
  }
}

// ---------- causal flash attention, paired q-tiles for uniform block cost ----------
__global__ __launch_bounds__(256) void attn_k(const unsigned short* __restrict__ qkv,
                                              unsigned short* __restrict__ o) {
  const int pi = blockIdx.x;          // 0..7
  const int pair = blockIdx.y;
  const int b = pair >> 4, h = pair & 15;
  const int t = threadIdx.x, wave = t >> 6, lane = t & 63;
  __shared__ __align__(16) unsigned short sQ[64 * 64];
  __shared__ __align__(16) unsigned short sK[2][64 * 64];
  __shared__ __align__(16) unsigned short sV[2][64 * 64];   // transposed [e][j]
  __shared__ __align__(16) unsigned short sP[4][16 * 64];

  const long baseq = (long)b * (1024 * 3072) + (long)h * 64;
  const unsigned short* qp = qkv + baseq;
  const unsigned short* kp = qkv + baseq + 1024;
  const unsigned short* vp = qkv + baseq + 2048;
  const long baseo = (long)b * (1024 * 1024) + (long)h * 64;

  const int row0 = t >> 3, c0 = t & 7;
  const int row1 = (t + 256) >> 3, c1 = t & 7;
  const int qoff0 = ((c0 ^ (row0 & 7)) << 3);
  const int qoff1 = ((c1 ^ (row1 & 7)) << 3);

  const int qrow = wave * 16 + (lane & 15);
  const int qswz0 = ((lane >> 4) << 4) ^ ((qrow & 7) << 4);
  const int prow = lane & 15;
  const f32x4 z4 = {0.f, 0.f, 0.f, 0.f};

  for (int half = 0; half < 2; ++half) {
    const int qt = half ? (15 - pi) : pi;
    __syncthreads();   // protect LDS reuse across halves

    gl_lds16(qp + (long)(qt * 64 + row0) * 3072 + qoff0, (char*)sQ + wave * 1024);
    gl_lds16(qp + (long)(qt * 64 + row1) * 3072 + qoff1, (char*)sQ + 4096 + wave * 1024);
    gl_lds16(kp + (long)(0 + row0) * 3072 + qoff0, (char*)sK[0] + wave * 1024);
    gl_lds16(kp + (long)(0 + row1) * 3072 + qoff1, (char*)sK[0] + 4096 + wave * 1024);
    bf16x8 vr0 = *(const bf16x8*)(vp + (long)row0 * 3072 + (c0 << 3));
    bf16x8 vr1 = *(const bf16x8*)(vp + (long)row1 * 3072 + (c1 << 3));
    {
      char* vb = (char*)sV[0];
#pragma unroll
      for (int j = 0; j < 8; ++j) {
        int e0 = (c0 << 3) + j, e1 = (c1 << 3) + j;
        *(unsigned short*)(vb + e0 * 128 + ((row0 * 2) ^ ((e0 & 7) << 4))) = (unsigned short)vr0[j];
        *(unsigned short*)(vb + e1 * 128 + ((row1 * 2) ^ ((e1 & 7) << 4))) = (unsigned short)vr1[j];
      }
    }
    __syncthreads();

    float lst[4] = {0.f, 0.f, 0.f, 0.f};
    f32x4 oacc[4];
#pragma unroll
    for (int eb = 0; eb < 4; ++eb) oacc[eb] = z4;

    for (int kt = 0; kt <= qt; ++kt) {
      const int cur = kt & 1;

      bf16x8 aq[2];
#pragma unroll
      for (int kk = 0; kk < 2; ++kk)
        aq[kk] = *(const bf16x8*)((char*)sQ + qrow * 128 + ((kk << 6) ^ qswz0));
      f32x4 sf[4];
#pragma unroll
      for (int cb = 0; cb < 4; ++cb) {
        f32x4 s = z4;
        int kr = cb * 16 + (lane & 15);
        int kswz = ((kr & 7) << 4);
#pragma unroll
        for (int kk = 0; kk < 2; ++kk) {
          int e0 = (kk * 32 + ((lane >> 4) << 3)) * 2;
          bf16x8 bk = *(const bf16x8*)((char*)sK[cur] + kr * 128 + (e0 ^ kswz));
          s = __builtin_amdgcn_mfma_f32_16x16x32_bf16(aq[kk], bk, s, 0, 0, 0);
        }
        sf[cb] = s;
      }

      if (kt < qt) {
        const int nxt = cur ^ 1;
        const long krb = (long)((kt + 1) * 64);
        gl_lds16(kp + (krb + row0) * 3072 + qoff0, (char*)sK[nxt] + wave * 1024);
        gl_lds16(kp + (krb + row1) * 3072 + qoff1, (char*)sK[nxt] + 4096 + wave * 1024);
        vr0 = *(const bf16x8*)(vp + (krb + row0) * 3072 + (c0 << 3));
        vr1 = *(const bf16x8*)(vp + (krb + row1) * 3072 + (c1 << 3));
      }

      const bool diag = (kt == qt);
      unsigned short* pb = sP[wave];
#pragma unroll
      for (int r = 0; r < 4; ++r) {
        int qg = wave * 16 + ((lane >> 4) << 2) + r;
        int lr = ((lane >> 4) << 2) + r;
        float rs = 0.f;
#pragma unroll
        for (int cb = 0; cb < 4; ++cb) {
          float p;
          if (diag) {
            int kg = cb * 16 + (lane & 15);
            p = (kg > qg) ? 0.f : __expf(sf[cb][r] * 0.125f);
          } else {
            p = __expf(sf[cb][r] * 0.125f);
          }
          rs += p;
          int col = cb * 16 + (lane & 15);
          *(unsigned short*)((char*)pb + lr * 128 + ((col * 2) ^ ((lr & 7) << 4))) = f2bf(p);
        }
        lst[r] += rs;
      }

      bf16x8 ap[2];
#pragma unroll
      for (int kk = 0; kk < 2; ++kk) {
        int j0 = (kk * 32 + ((lane >> 4) << 3)) * 2;
        ap[kk] = *(const bf16x8*)((char*)pb + prow * 128 + (j0 ^ ((prow & 7) << 4)));
      }
#pragma unroll
      for (int eb = 0; eb < 4; ++eb) {
        int er = eb * 16 + (lane & 15);
        int eswz = ((er & 7) << 4);
#pragma unroll
        for (int kk = 0; kk < 2; ++kk) {
          int j0 = (kk * 32 + ((lane >> 4) << 3)) * 2;
          bf16x8 bv = *(const bf16x8*)((char*)sV[cur] + er * 128 + (j0 ^ eswz));
          oacc[eb] = __builtin_amdgcn_mfma_f32_16x16x32_bf16(ap[kk], bv, oacc[eb], 0, 0, 0);
        }
      }

      if (kt < qt) {
        char* vb = (char*)sV[cur ^ 1];
#pragma unroll
        for (int j = 0; j < 8; ++j) {
          int e0 = (c0 << 3) + j, e1 = (c1 << 3) + j;
          *(unsigned short*)(vb + e0 * 128 + ((row0 * 2) ^ ((e0 & 7) << 4))) = (unsigned short)vr0[j];
          *(unsigned short*)(vb + e1 * 128 + ((row1 * 2) ^ ((e1 & 7) << 4))) = (unsigned short)vr1[j];
        }
        __syncthreads();
      }
    }

#pragma unroll
    for (int r = 0; r < 4; ++r) {
      float l = lst[r];
#pragma unroll
      for (int d = 1; d < 16; d <<= 1) l += __shfl_xor(l, d, 64);
      float inv = 1.f / l;
      int qg = qt * 64 + wave * 16 + ((lane >> 4) << 2) + r;
#pragma unroll
      for (int eb = 0; eb < 4; ++eb) {
        int e = eb * 16 + (lane & 15);
        o[baseo + (long)qg * 1024 + e] = f2bf(oacc[eb][r] * inv);
      }
    }
  }
}

// ---------- host launch ----------
extern "C" void kernel_launch(void* const* d_in, const int* in_sizes, int n_in,
                              void* d_out, int out_size, void* d_ws, size_t ws_size,
                              hipStream_t stream) {
  const int* idx = (const int*)d_in[0];
  const float* tok = (const float*)d_in[1];
  const float* pos = (const float*)d_in[2];
  const float* Wq = (const float*)d_in[3];
  const float* Wk = (const float*)d_in[4];
  const float* Wv = (const float*)d_in[5];
  const float* Wo = (const float*)d_in[6];
  const float* bo = (const float*)d_in[7];
  const float* ln1g = (const float*)d_in[8];
  const float* ln1b = (const float*)d_in[9];
  const float* ln2g = (const float*)d_in[10];
  const float* ln2b = (const float*)d_in[11];
  const float* W1 = (const float*)d_in[12];
  const float* b1 = (const float*)d_in[13];
  const float* W2 = (const float*)d_in[14];
  const float* b2 = (const float*)d_in[15];
  const float* lnfg = (const float*)d_in[16];
  const float* lnfb = (const float*)d_in[17];
  const float* Wh = (const float*)d_in[18];
  const float* bh = (const float*)d_in[19];

  char* ws = (char*)d_ws;
  const long Mi = 1024 * 1024;
  float* x = (float*)ws;
  unsigned short* xn = (unsigned short*)(ws + 16 * Mi);
  unsigned short* qkv = (unsigned short*)(ws + 24 * Mi);
  unsigned short* ob = (unsigned short*)(ws + 48 * Mi);
  unsigned short* hmid = (unsigned short*)(ws + 24 * Mi);
  unsigned short* wqkvT = (unsigned short*)(ws + 56 * Mi);
  unsigned short* whT = (unsigned short*)(ws + 56 * Mi);   // alias (post-loop)

  const bool bigws = (ws_size >= (size_t)250 * 1024 * 1024);
  unsigned short* wotA = (unsigned short*)(ws + 104 * Mi);
  unsigned short* w1tA = (unsigned short*)(ws + 120 * Mi);
  unsigned short* w2tA = (unsigned short*)(ws + 184 * Mi);
  unsigned short* wot1 = (unsigned short*)(ws + 104 * Mi);
  unsigned short* w1t1 = (unsigned short*)(ws + 106 * Mi);
  unsigned short* w2t1 = (unsigned short*)(ws + 114 * Mi);

  dim3 blk256(256), blk512(512), blkT(32, 8);

  embed_k<<<4096, blk256, 0, stream>>>(idx, tok, pos, x);
  tr_qkv_k<<<dim3(2, 32, 384), blkT, 0, stream>>>(Wq, Wk, Wv, wqkvT);
  if (bigws) {
    tr_k<<<dim3(32, 32, 8), blkT, 0, stream>>>(Wo, wotA, 1024, 1024, 1048576, 1048576);
    tr_k<<<dim3(128, 32, 8), blkT, 0, stream>>>(W1, w1tA, 1024, 4096, 4194304, 4194304);
    tr_k<<<dim3(32, 128, 8), blkT, 0, stream>>>(W2, w2tA, 4096, 1024, 4194304, 4194304);
  }

  for (int l = 0; l < 8; ++l) {
    const float* bo_l = bo + (long)l * 1024;
    const float* b1_l = b1 + (long)l * 4096;
    const float* b2_l = b2 + (long)l * 1024;
    const unsigned short* wqkv_l = wqkvT + (long)l * (3072 * 1024);

    const unsigned short* wot_l;
    const unsigned short* w1t_l;
    const unsigned short* w2t_l;
    if (bigws) {
      wot_l = wotA + (long)l * 1048576;
      w1t_l = w1tA + (long)l * 4194304;
      w2t_l = w2tA + (long)l * 4194304;
    } else {
      tr_k<<<dim3(32, 32, 1), blkT, 0, stream>>>(Wo + (long)l * 1048576, wot1, 1024, 1024, 0, 0);
      tr_k<<<dim3(128, 32, 1), blkT, 0, stream>>>(W1 + (long)l * 4194304, w1t1, 1024, 4096, 0, 0);
      tr_k<<<dim3(32, 128, 1), blkT, 0, stream>>>(W2 + (long)l * 4194304, w2t1, 4096, 1024, 0, 0);
      wot_l = wot1; w1t_l = w1t1; w2t_l = w2t1;
    }

    ln_k<<<4096, blk256, 0, stream>>>(x, ln1g + l * 1024, ln1b + l * 1024, xn);

    gemm256<0><<<dim3(12, 16), blk512, 0, stream>>>(xn, wqkv_l, nullptr, qkv, nullptr, 4096, 3072, 1024);

    attn_k<<<dim3(8, 64), blk256, 0, stream>>>(qkv, ob);

    gemm_bt<1><<<dim3(8, 32), blk256, 0, stream>>>(ob, wot_l, x, nullptr, bo_l, x, 4096, 1024, 1024);

    ln_k<<<4096, blk256, 0, stream>>>(x, ln2g + l * 1024, ln2b + l * 1024, xn);

    gemm256<2><<<dim3(16, 16), blk512, 0, stream>>>(xn, w1t_l, nullptr, hmid, b1_l, 4096, 4096, 1024);
    gemm_bt<1><<<dim3(8, 32), blk256, 0, stream>>>(hmid, w2t_l, x, nullptr, b2_l, x, 4096, 1024, 4096);
  }

  ln_k<<<4096, blk256, 0, stream>>>(x, lnfg, lnfb, xn);
  tr_k<<<dim3(1000, 32, 1), blkT, 0, stream>>>(Wh, whT, 1024, 32000, 0, 0);
  gemm256<3><<<dim3(125, 16), blk512, 0, stream>>>(xn, whT, (float*)d_out, nullptr, bh, 4096, 32000, 1024);
}